// Round 18
// baseline (237.836 us; speedup 1.0000x reference)
//
#include <hip/hip_runtime.h>
#include <math.h>

#define NNODES 50000
#define MINC   200000
#define NEDGE  20000
#define NIND   8

// log2(e) folded into score/K scales so softmax uses exp2 (native v_exp_f32)
#define SCALE_LOG2E 0.18033688f   // 0.125 * log2(e)

typedef __attribute__((ext_vector_type(8))) short bf16x8;
typedef __attribute__((ext_vector_type(4))) float f32x4;

__device__ __forceinline__ short f2bf(float f) {
    union { float f; unsigned u; } x; x.f = f;
    unsigned r = x.u + 0x7FFF + ((x.u >> 16) & 1);
    return (short)(r >> 16);
}
__device__ __forceinline__ float bf2f(short s) {
    union { unsigned u; float f; } x; x.u = ((unsigned)(unsigned short)s) << 16;
    return x.f;
}
__device__ __forceinline__ int qperm(int c) { return ((c & 15) << 2) | (c >> 4); }
__device__ __forceinline__ int sigperm(int c) { return ((c & 3) << 4) | (c >> 2); }

// ====== MERGED: setup (blocks 0-5) ∥ histogram (blocks 6..396), 512 thr ======
__global__ void setup_hist_kernel(const float* __restrict__ I,
                                  const float* __restrict__ m0_wq, const float* __restrict__ m0_bq,
                                  const float* __restrict__ m0_wk, const float* __restrict__ m0_bk,
                                  const float* __restrict__ m0_wv, const float* __restrict__ m0_bv,
                                  const float* __restrict__ m1_wq, const float* __restrict__ m1_bq,
                                  const float* __restrict__ m0_wo, const float* __restrict__ m1_wk,
                                  const float* __restrict__ m1_wv, const float* __restrict__ m1_wo,
                                  float* __restrict__ QI, float* __restrict__ bias160,
                                  short* __restrict__ Wt0, short* __restrict__ WtO,
                                  short* __restrict__ WtK, short* __restrict__ WtV,
                                  short* __restrict__ WtF,
                                  const int* __restrict__ edge, int* __restrict__ cnt) {
    __shared__ float QIs[512];
    __shared__ float Wf[2048];
    __shared__ float bfS[32];
    int tid = threadIdx.x, bid = blockIdx.x;
    if (bid >= 6) {           // histogram part (cnt pre-zeroed by memsetAsync)
        int m = (bid - 6) * 512 + tid;
        if (m < MINC) atomicAdd(&cnt[edge[m]], 1);
        return;
    }
    {
        int i = tid >> 6, c = tid & 63;
        float acc = m0_bq[c];
        for (int k = 0; k < 64; ++k) acc += I[i * 64 + k] * m0_wq[k * 64 + c];
        QIs[tid] = acc;
    }
    __syncthreads();
    if (bid == 0) {
        QI[tid] = QIs[tid];
        if (tid < 32) {
            int i = tid >> 2, h = tid & 3;
            float s = 0.f;
            for (int d = 0; d < 16; ++d)
                s += m0_bk[h * 16 + d] * QIs[i * 64 + h * 16 + d];
            bfS[tid] = s * SCALE_LOG2E;
        }
        __syncthreads();
        if (tid < 160)
            bias160[tid] = (tid < 64) ? m0_bv[tid]
                         : ((tid < 96) ? bfS[tid - 64] : m1_bq[tid - 96]);
    } else if (bid == 1) {
        for (int idx = tid; idx < 2048; idx += 512) {
            int k = idx >> 5, j = idx & 31;
            int i = j >> 2, h = j & 3;
            float s = 0.f;
            for (int d = 0; d < 16; ++d)
                s += m0_wk[k * 64 + h * 16 + d] * QIs[i * 64 + h * 16 + d];
            Wf[idx] = s * SCALE_LOG2E;
        }
        __syncthreads();
        for (int idx = tid; idx < 160 * 72; idx += 512) {
            int c = idx / 72, k = idx % 72;
            short v = 0;
            if (k < 64) {
                float f = (c < 64) ? m0_wv[k * 64 + c]
                        : (c < 96) ? Wf[k * 32 + (c - 64)]
                                   : m1_wq[k * 64 + (c - 96)];
                v = f2bf(f);
            }
            Wt0[idx] = v;
        }
    } else {
        int mat = bid - 2;
        const float* W = (mat == 0) ? m0_wo : (mat == 1) ? m1_wk : (mat == 2) ? m1_wv : m1_wo;
        short* D = (mat == 0) ? WtO : (mat == 1) ? WtK : (mat == 2) ? WtV : WtF;
        bool cperm = (mat == 0);
        for (int idx = tid; idx < 64 * 72; idx += 512) {
            int c = idx / 72, k = idx % 72;
            short v = 0;
            if (k < 64) {
                int kk = qperm(k);
                int cc = cperm ? qperm(c) : c;
                v = f2bf(W[kk * 64 + cc]);
            }
            D[idx] = v;
        }
    }
}

// ====== MERGED: segment-base alloc (blocks 0..78, wave atomic bump) ∥ X GEMM ======
#define NALLOCB ((NEDGE + 255) / 256)   // 79
__global__ void gemmx_alloc_kernel(const float* __restrict__ A,
                                   const short* __restrict__ Wt, const float* __restrict__ bias,
                                   short* __restrict__ V0, _Float16* __restrict__ S0,
                                   short* __restrict__ Q1,
                                   const int* __restrict__ cnt, int2* __restrict__ rowcnt,
                                   int* __restrict__ cursor, int* __restrict__ total) {
    __shared__ short As[64 * 72];
    __shared__ short Ws[160 * 72];
    int tid = threadIdx.x;     // 256
    if (blockIdx.x < NALLOCB) {   // -------- alloc part --------
        int e = blockIdx.x * 256 + tid;
        int lane = tid & 63;
        int c = (e < NEDGE) ? cnt[e] : 0;
        int v = c;
        #pragma unroll
        for (int off = 1; off < 64; off <<= 1) {
            int t = __shfl_up(v, off);
            if (lane >= off) v += t;
        }
        int wavesum = __shfl(v, 63);
        int base = 0;
        if (lane == 63) base = atomicAdd(total, wavesum);
        base = __shfl(base, 63);
        int excl = base + v - c;
        if (e < NEDGE) {
            rowcnt[e] = make_int2(excl, c);
            cursor[e] = excl;
        }
        return;
    }
    // -------- gemm_x part --------
    int row0 = (blockIdx.x - NALLOCB) * 64;
    {
        const uint4* wsrc = (const uint4*)Wt;
        uint4* wdst = (uint4*)Ws;
        for (int k = tid; k < 1440; k += 256) wdst[k] = wsrc[k];
    }
    {
        int r = tid >> 2, c0 = (tid & 3) * 16;
        int gr = row0 + r;
        float f[16];
        if (gr < NNODES) {
            const float4* src = (const float4*)(A + (size_t)gr * 64 + c0);
            #pragma unroll
            for (int j = 0; j < 4; ++j) {
                float4 t4 = src[j];
                f[4*j] = t4.x; f[4*j+1] = t4.y; f[4*j+2] = t4.z; f[4*j+3] = t4.w;
            }
        } else {
            #pragma unroll
            for (int j = 0; j < 16; ++j) f[j] = 0.f;
        }
        short tmp[16];
        #pragma unroll
        for (int j = 0; j < 16; ++j) tmp[j] = f2bf(f[j]);
        uint4* dst = (uint4*)&As[r * 72 + c0];
        dst[0] = *(const uint4*)&tmp[0];
        dst[1] = *(const uint4*)&tmp[8];
    }
    __syncthreads();
    int w = tid >> 6, l = tid & 63;
    int lr16 = l & 15, lk = (l >> 4) * 8;
    f32x4 acc[10] = {};
    #pragma unroll
    for (int ks = 0; ks < 2; ++ks) {
        bf16x8 a = *(const bf16x8*)&As[(w * 16 + lr16) * 72 + ks * 32 + lk];
        #pragma unroll
        for (int t = 0; t < 10; ++t) {
            bf16x8 b = *(const bf16x8*)&Ws[(t * 16 + lr16) * 72 + ks * 32 + lk];
            acc[t] = __builtin_amdgcn_mfma_f32_16x16x32_bf16(a, b, acc[t], 0, 0, 0);
        }
    }
    int rbase = w * 16 + (l >> 4) * 4;
    #pragma unroll
    for (int t = 0; t < 10; ++t) {
        int c = t * 16 + lr16;
        float bb = bias[c];
        #pragma unroll
        for (int r = 0; r < 4; ++r) {
            int gr = row0 + rbase + r;
            if (gr < NNODES) {
                float val = acc[t][r] + bb;
                if (c < 64) V0[(size_t)gr * 64 + c] = f2bf(val);
                else if (c < 96) S0[(size_t)gr * 32 + (c - 64)] = (_Float16)val;
                else Q1[(size_t)gr * 64 + (c - 96)] = f2bf(val);
            }
        }
    }
}

__global__ void scatter_kernel(const int* __restrict__ node, const int* __restrict__ edge,
                               int* __restrict__ cursor, int2* __restrict__ csr_nm) {
    int m = blockIdx.x * 256 + threadIdx.x;
    if (m < MINC) {
        int e = edge[m];
        int pos = atomicAdd(&cursor[e], 1);
        csr_nm[pos] = make_int2(node[m], m);
    }
}

// ============ mab0 attention: ONE WAVE PER EDGE, LDS index staging, paired PV ============
#define CH0 32
__global__ void attn0_kernel(const short* __restrict__ V0, const _Float16* __restrict__ S0,
                             const float* __restrict__ QI,
                             const int2* __restrict__ rowcnt, const int2* __restrict__ csr_nm,
                             short* __restrict__ Opre0) {
    __shared__ float Sw[4][CH0][32];
    __shared__ float Sc[4][32];
    __shared__ float Li[4][32];
    __shared__ int   Ns[4][CH0];
    int w = threadIdx.x >> 6;
    int lane = threadIdx.x & 63;
    int e = blockIdx.x * 4 + w;
    int2 rc = rowcnt[e];
    int start = rc.x, end = rc.x + rc.y;
    int j = lane & 31;                       // i*4+h
    int pslot = lane >> 5;
    int tj = ((j & 3) << 3) | (j >> 2);      // h*8+i
    int col2 = lane & 31;                    // packed col pair: dims 2*col2, 2*col2+1
    int hh = col2 >> 3;                      // head for PV weights
    float runm = -INFINITY, lrun = 0.f;
    float accL[8] = {}, accH[8] = {};
    for (int c0 = start; c0 < end; c0 += CH0) {
        int cnt = min(CH0, end - c0);
        if (lane < CH0) {
            int idx = c0 + min(lane, cnt - 1);
            Ns[w][lane] = csr_nm[idx].x;
        }
        asm volatile("s_waitcnt lgkmcnt(0)" ::: "memory");
        __builtin_amdgcn_sched_barrier(0);
        float cm = -INFINITY;
        for (int p = pslot; p < cnt; p += 2) {
            int n = Ns[w][p];
            float s = (float)S0[(size_t)n * 32 + j];
            Sw[w][p][tj] = s;
            cm = fmaxf(cm, s);
        }
        cm = fmaxf(cm, __shfl_xor(cm, 32));
        float newm = fmaxf(runm, cm);
        float sc = exp2f(runm - newm);
        runm = newm;
        float lsum = 0.f;
        for (int p = pslot; p < cnt; p += 2) {
            float s = Sw[w][p][tj];
            float w_ = exp2f(s - newm);
            Sw[w][p][tj] = w_;
            lsum += w_;
        }
        lsum += __shfl_xor(lsum, 32);
        lrun = lrun * sc + lsum;
        if (pslot == 0) Sc[w][tj] = sc;
        asm volatile("s_waitcnt lgkmcnt(0)" ::: "memory");
        __builtin_amdgcn_sched_barrier(0);
        float4 sA = *(const float4*)&Sc[w][hh * 8];
        float4 sB = *(const float4*)&Sc[w][hh * 8 + 4];
        accL[0] *= sA.x; accH[0] *= sA.x;
        accL[1] *= sA.y; accH[1] *= sA.y;
        accL[2] *= sA.z; accH[2] *= sA.z;
        accL[3] *= sA.w; accH[3] *= sA.w;
        accL[4] *= sB.x; accH[4] *= sB.x;
        accL[5] *= sB.y; accH[5] *= sB.y;
        accL[6] *= sB.z; accH[6] *= sB.z;
        accL[7] *= sB.w; accH[7] *= sB.w;
        int npair = (cnt + 1) >> 1;
        #pragma unroll 4
        for (int k = 0; k < npair; ++k) {
            int rp = 2 * k + pslot;
            bool vld = rp < cnt;
            int rc2 = vld ? rp : (cnt - 1);
            int n = Ns[w][rc2];
            unsigned vp = *(const unsigned*)&V0[(size_t)n * 64 + col2 * 2];
            float vlo = vld ? __int_as_float(vp << 16) : 0.f;
            float vhi = vld ? __int_as_float(vp & 0xffff0000u) : 0.f;
            float4 wA = *(const float4*)&Sw[w][rc2][hh * 8];
            float4 wB = *(const float4*)&Sw[w][rc2][hh * 8 + 4];
            accL[0] += wA.x * vlo; accH[0] += wA.x * vhi;
            accL[1] += wA.y * vlo; accH[1] += wA.y * vhi;
            accL[2] += wA.z * vlo; accH[2] += wA.z * vhi;
            accL[3] += wA.w * vlo; accH[3] += wA.w * vhi;
            accL[4] += wB.x * vlo; accH[4] += wB.x * vhi;
            accL[5] += wB.y * vlo; accH[5] += wB.y * vhi;
            accL[6] += wB.z * vlo; accH[6] += wB.z * vhi;
            accL[7] += wB.w * vlo; accH[7] += wB.w * vhi;
        }
    }
    if (pslot == 0) Li[w][tj] = lrun;
    asm volatile("s_waitcnt lgkmcnt(0)" ::: "memory");
    __builtin_amdgcn_sched_barrier(0);
    #pragma unroll
    for (int i = 0; i < 8; ++i) {
        accL[i] += __shfl_xor(accL[i], 32);
        accH[i] += __shfl_xor(accH[i], 32);
    }
    float4 lA = *(const float4*)&Li[w][hh * 8];
    float4 lB = *(const float4*)&Li[w][hh * 8 + 4];
    float li[8] = {lA.x, lA.y, lA.z, lA.w, lB.x, lB.y, lB.z, lB.w};
    if (pslot == 0) {
        #pragma unroll
        for (int i = 0; i < 8; ++i) {
            float2 qi2 = *(const float2*)&QI[i * 64 + col2 * 2];
            float inv = (li[i] > 0.f) ? 1.f / li[i] : 0.f;
            float ol = qi2.x + accL[i] * inv;
            float oh = qi2.y + accH[i] * inv;
            unsigned res = ((unsigned)(unsigned short)f2bf(oh) << 16)
                         | (unsigned)(unsigned short)f2bf(ol);
            *(unsigned*)&Opre0[(size_t)(e * NIND + i) * 64 + col2 * 2] = res;
        }
    }
}

// === MERGED fused_hkv + attn1 (64 rows = 8 edges per block), weights direct from L1/L2 ===
__global__ __launch_bounds__(256, 8)
void fused_hkv_attn1_kernel(const short* __restrict__ Opre0,
                            const short* __restrict__ WtO, const float* __restrict__ bo,
                            const short* __restrict__ WtK, const float* __restrict__ bk,
                            const short* __restrict__ WtV, const float* __restrict__ bv,
                            const short* __restrict__ Q1,
                            const int2* __restrict__ rowcnt,
                            const int2* __restrict__ csr_nm,
                            short* __restrict__ Opre1) {
    __shared__ short As[64 * 72];     // A -> H -> K(prescaled)
    __shared__ short Vls[64 * 72];    // V
    int tid = threadIdx.x;   // 256
    int row0 = blockIdx.x * 64;   // 160000 % 64 == 0
    {
        int r = tid >> 2, c0 = (tid & 3) * 16;
        const uint4* src = (const uint4*)(Opre0 + (size_t)(row0 + r) * 64 + c0);
        uint4* dst = (uint4*)&As[r * 72 + c0];
        dst[0] = src[0]; dst[1] = src[1];
    }
    __syncthreads();
    int w = tid >> 6, lane = tid & 63;
    int lr16 = lane & 15, lk = (lane >> 4) * 8;
    int rbase = w * 16 + (lane >> 4) * 4;
    {   // GEMM1: H in-place (wave w only touches rows [w*16, (w+1)*16))
        f32x4 acc[4] = {};
        #pragma unroll
        for (int ks = 0; ks < 2; ++ks) {
            bf16x8 a = *(const bf16x8*)&As[(w * 16 + lr16) * 72 + ks * 32 + lk];
            #pragma unroll
            for (int t = 0; t < 4; ++t) {
                bf16x8 b = *(const bf16x8*)&WtO[(t * 16 + lr16) * 72 + ks * 32 + lk];
                acc[t] = __builtin_amdgcn_mfma_f32_16x16x32_bf16(a, b, acc[t], 0, 0, 0);
            }
        }
        #pragma unroll
        for (int t = 0; t < 4; ++t) {
            int c = t * 16 + lr16;
            float bb = bo[qperm(c)];
            #pragma unroll
            for (int r = 0; r < 4; ++r) {
                float res = bf2f(As[(rbase + r) * 72 + c]);
                float hv = res + fmaxf(acc[t][r] + bb, 0.f);
                As[(rbase + r) * 72 + c] = f2bf(hv);
            }
        }
    }
    {   // GEMM2/3 -> K (prescaled) overwrites As rows; V -> Vls (all wave-private)
        f32x4 ak[4] = {}, av[4] = {};
        #pragma unroll
        for (int ks = 0; ks < 2; ++ks) {
            bf16x8 a = *(const bf16x8*)&As[(w * 16 + lr16) * 72 + ks * 32 + lk];
            #pragma unroll
            for (int t = 0; t < 4; ++t) {
                bf16x8 b1 = *(const bf16x8*)&WtK[(t * 16 + lr16) * 72 + ks * 32 + lk];
                ak[t] = __builtin_amdgcn_mfma_f32_16x16x32_bf16(a, b1, ak[t], 0, 0, 0);
                bf16x8 b2 = *(const bf16x8*)&WtV[(t * 16 + lr16) * 72 + ks * 32 + lk];
                av[t] = __builtin_amdgcn_mfma_f32_16x16x32_bf16(a, b2, av[t], 0, 0, 0);
            }
        }
        #pragma unroll
        for (int t = 0; t < 4; ++t) {
            int c = t * 16 + lr16;
            float bbk = bk[c], bbv = bv[c];
            #pragma unroll
            for (int r = 0; r < 4; ++r) {
                int rr = rbase + r;
                As[rr * 72 + c]  = f2bf((ak[t][r] + bbk) * SCALE_LOG2E);
                Vls[rr * 72 + c] = f2bf(av[t][r] + bbv);
            }
        }
    }
    // ---- attn1 phase: each wave handles its OWN 2 edges; K/V from wave-private LDS ----
    int sl4 = lane & 15;
    int inc = lane >> 4;
    for (int le = 0; le < 2; ++le) {
        int eloc = w * 2 + le;               // 0..7
        int e = blockIdx.x * 8 + eloc;
        int lr0 = eloc * 8;                  // local row base (within wave-own rows)
        float Kf[8][4], Vf[8][4];
        #pragma unroll
        for (int i = 0; i < 8; ++i) {
            uint2 kp = *(const uint2*)&As[(lr0 + i) * 72 + sl4 * 4];
            uint2 vp = *(const uint2*)&Vls[(lr0 + i) * 72 + sl4 * 4];
            Kf[i][0] = __int_as_float(kp.x << 16);
            Kf[i][1] = __int_as_float(kp.x & 0xffff0000u);
            Kf[i][2] = __int_as_float(kp.y << 16);
            Kf[i][3] = __int_as_float(kp.y & 0xffff0000u);
            Vf[i][0] = __int_as_float(vp.x << 16);
            Vf[i][1] = __int_as_float(vp.x & 0xffff0000u);
            Vf[i][2] = __int_as_float(vp.y << 16);
            Vf[i][3] = __int_as_float(vp.y & 0xffff0000u);
        }
        #pragma unroll
        for (int i = 0; i < 8; ++i) {
            #pragma unroll
            for (int d = 0; d < 4; ++d) {
                asm volatile("" : "+v"(Kf[i][d]), "+v"(Vf[i][d]));
            }
        }
        int2 rc = rowcnt[e];
        int start = rc.x, end = rc.x + rc.y;
        #pragma unroll 4
        for (int p0 = start; p0 < end; p0 += 4) {
            int p = p0 + inc;
            bool valid = (p < end);
            int pc = valid ? p : (end - 1);
            int2 nm = csr_nm[pc];
            uint2 qp = *(const uint2*)&Q1[(size_t)nm.x * 64 + sl4 * 4];
            float qa0 = __int_as_float(qp.x << 16);
            float qa1 = __int_as_float(qp.x & 0xffff0000u);
            float qa2 = __int_as_float(qp.y << 16);
            float qa3 = __int_as_float(qp.y & 0xffff0000u);
            float a[8];
            #pragma unroll
            for (int i = 0; i < 8; ++i) {
                float t = qa0 * Kf[i][0] + qa1 * Kf[i][1] + qa2 * Kf[i][2] + qa3 * Kf[i][3];
                int tv = __builtin_amdgcn_update_dpp(0, __float_as_int(t), 0xB1, 0xf, 0xf, true);
                t += __int_as_float(tv);
                tv = __builtin_amdgcn_update_dpp(0, __float_as_int(t), 0x4E, 0xf, 0xf, true);
                t += __int_as_float(tv);
                a[i] = t;                                 // log2-domain score
            }
            float mx = fmaxf(fmaxf(fmaxf(a[0], a[1]), fmaxf(a[2], a[3])),
                             fmaxf(fmaxf(a[4], a[5]), fmaxf(a[6], a[7])));
            float l = 0.f, ac0 = 0.f, ac1 = 0.f, ac2 = 0.f, ac3 = 0.f;
            #pragma unroll
            for (int i = 0; i < 8; ++i) {
                float w_ = exp2f(a[i] - mx);
                l += w_;
                ac0 += w_ * Vf[i][0];
                ac1 += w_ * Vf[i][1];
                ac2 += w_ * Vf[i][2];
                ac3 += w_ * Vf[i][3];
            }
            float rl = 1.f / l;
            float o0 = qa0 + ac0 * rl;
            float o1 = qa1 + ac1 * rl;
            float o2 = qa2 + ac2 * rl;
            float o3 = qa3 + ac3 * rl;
            uint2 res;
            res.x = ((unsigned)(unsigned short)f2bf(o1) << 16) | (unsigned)(unsigned short)f2bf(o0);
            res.y = ((unsigned)(unsigned short)f2bf(o3) << 16) | (unsigned)(unsigned short)f2bf(o2);
            if (valid) *(uint2*)&Opre1[(size_t)nm.y * 64 + sl4 * 4] = res;
        }
    }
}

// ======= final GEMM (128 rows/block): out = res + relu(A@w+b), perm baked, NT stores =======
__global__ void gemm_out_kernel(const short* __restrict__ Av,
                                const short* __restrict__ Wt, const float* __restrict__ bias,
                                float* __restrict__ out) {
    __shared__ short As[128 * 72];
    __shared__ short Ws[64 * 72];
    int tid = threadIdx.x;     // 256
    int row0 = blockIdx.x * 128;
    {
        const uint4* wsrc = (const uint4*)Wt;
        uint4* wdst = (uint4*)Ws;
        for (int k = tid; k < 576; k += 256) wdst[k] = wsrc[k];
    }
    #pragma unroll
    for (int it = 0; it < 2; ++it) {
        int slot = tid + it * 256;
        int r = slot >> 2, c0 = (slot & 3) * 16;
        int gr = row0 + r;
        uint4 a0 = {}, a1 = {};
        if (gr < MINC) {
            const uint4* src = (const uint4*)(Av + (size_t)gr * 64 + c0);
            a0 = src[0]; a1 = src[1];
        }
        uint4* dst = (uint4*)&As[r * 72 + c0];
        dst[0] = a0; dst[1] = a1;
    }
    __syncthreads();
    int w = tid >> 6, l = tid & 63;
    int lr16 = l & 15, lk = (l >> 4) * 8;
    f32x4 acc[2][4] = {};
    #pragma unroll
    for (int ks = 0; ks < 2; ++ks) {
        bf16x8 a0 = *(const bf16x8*)&As[(w * 16 + lr16) * 72 + ks * 32 + lk];
        bf16x8 a1 = *(const bf16x8*)&As[(64 + w * 16 + lr16) * 72 + ks * 32 + lk];
        #pragma unroll
        for (int t = 0; t < 4; ++t) {
            bf16x8 b = *(const bf16x8*)&Ws[(t * 16 + lr16) * 72 + ks * 32 + lk];
            acc[0][t] = __builtin_amdgcn_mfma_f32_16x16x32_bf16(a0, b, acc[0][t], 0, 0, 0);
            acc[1][t] = __builtin_amdgcn_mfma_f32_16x16x32_bf16(a1, b, acc[1][t], 0, 0, 0);
        }
    }
    int rbase = w * 16 + (l >> 4) * 4;
    #pragma unroll
    for (int rt = 0; rt < 2; ++rt) {
        #pragma unroll
        for (int t = 0; t < 4; ++t) {
            int c = t * 16 + lr16;
            float bb = bias[c];
            int sc = sigperm(c);
            #pragma unroll
            for (int r = 0; r < 4; ++r) {
                int gr = row0 + rt * 64 + rbase + r;
                if (gr < MINC) {
                    float val = acc[rt][t][r] + bb;
                    float res = bf2f(As[(rt * 64 + rbase + r) * 72 + sc]);
                    __builtin_nontemporal_store(res + fmaxf(val, 0.f),
                                                &out[(size_t)gr * 64 + c]);
                }
            }
        }
    }
}

// ===================== host launch =====================
extern "C" void kernel_launch(void* const* d_in, const int* in_sizes, int n_in,
                              void* d_out, int out_size, void* d_ws, size_t ws_size,
                              hipStream_t stream) {
    const float* X    = (const float*)d_in[0];
    const int*   hei  = (const int*)d_in[1];
    const float* I    = (const float*)d_in[2];
    const float* m0_wq = (const float*)d_in[3];
    const float* m0_bq = (const float*)d_in[4];
    const float* m0_wk = (const float*)d_in[5];
    const float* m0_bk = (const float*)d_in[6];
    const float* m0_wv = (const float*)d_in[7];
    const float* m0_bv = (const float*)d_in[8];
    const float* m0_wo = (const float*)d_in[9];
    const float* m0_bo = (const float*)d_in[10];
    const float* m1_wq = (const float*)d_in[11];
    const float* m1_bq = (const float*)d_in[12];
    const float* m1_wk = (const float*)d_in[13];
    const float* m1_bk = (const float*)d_in[14];
    const float* m1_wv = (const float*)d_in[15];
    const float* m1_bv = (const float*)d_in[16];
    const float* m1_wo = (const float*)d_in[17];
    const float* m1_bo = (const float*)d_in[18];

    const int* node = hei;           // [M]
    const int* edge = hei + MINC;    // [M]
    float* out = (float*)d_out;

    // -------- workspace layout (byte offsets) --------
    char* B = (char*)d_ws;
    short* Opre0 = (short*)B;                    // 20.48 MB
    short* V0    = (short*)(B + 20480000);       // 6.4 MB
    _Float16* S0 = (_Float16*)(B + 26880000);    // 3.2 MB
    short* Opre1 = (short*)(B + 33280000);       // 25.6 MB
    short* Q1    = (short*)(B + 74240000);       // 6.4 MB
    float* QI    = (float*)(B + 80640000);       // 512 f
    float* bias160 = QI + 512;                   // 160 f
    short* PK    = (short*)(bias160 + 160);
    short* Wt0   = PK;                           // 160*72
    short* WtO   = PK + 11520;
    short* WtK   = WtO + 4608;
    short* WtV   = WtK + 4608;
    short* WtF   = WtV + 4608;
    int*   ib       = (int*)(((size_t)(WtF + 4608) + 7) & ~(size_t)7);
    int2*  rowcnt   = (int2*)ib;                 // NE int2
    int*   cnt      = (int*)(rowcnt + NEDGE);    // NE  (memset region starts here)
    int*   total    = cnt + NEDGE;               // 1   (zeroed with cnt)
    int*   cursor   = total + 1;                 // NE
    int2*  csr_nm   = (int2*)(((size_t)(cursor + NEDGE) + 7) & ~(size_t)7);  // M int2

    // ---------------- setup ∥ hist, then alloc ∥ gemm_x, then scatter ----------------
    hipMemsetAsync(cnt, 0, (NEDGE + 1) * sizeof(int), stream);
    setup_hist_kernel<<<6 + (MINC + 511) / 512, 512, 0, stream>>>(
        I, m0_wq, m0_bq, m0_wk, m0_bk, m0_wv, m0_bv,
        m1_wq, m1_bq, m0_wo, m1_wk, m1_wv, m1_wo,
        QI, bias160, Wt0, WtO, WtK, WtV, WtF, edge, cnt);
    gemmx_alloc_kernel<<<NALLOCB + (NNODES + 63) / 64, 256, 0, stream>>>(
        X, Wt0, bias160, V0, S0, Q1, cnt, rowcnt, cursor, total);
    scatter_kernel<<<(MINC + 255) / 256, 256, 0, stream>>>(node, edge, cursor, csr_nm);

    // ---------------- Phase A: mab0 ----------------
    attn0_kernel<<<NEDGE / 4, 256, 0, stream>>>(V0, S0, QI, rowcnt, csr_nm, Opre0);

    // ---------------- Phase B: mab1 (fused H/K/V GEMMs + attention) ----------------
    fused_hkv_attn1_kernel<<<NEDGE / 8, 256, 0, stream>>>(
        Opre0, WtO, m0_bo, WtK, m1_bk, WtV, m1_bv, Q1, rowcnt, csr_nm, Opre1);
    gemm_out_kernel<<<(MINC + 127) / 128, 256, 0, stream>>>(Opre1, WtF, m1_bo, out);
}

// Round 19
// 146.609 us; speedup vs baseline: 1.6223x; 1.6223x over previous
//
#include <hip/hip_runtime.h>
#include <math.h>

#define NNODES 50000
#define MINC   200000
#define NEDGE  20000
#define NIND   8

// log2(e) folded into score/K scales so softmax uses exp2 (native v_exp_f32)
#define SCALE_LOG2E 0.18033688f   // 0.125 * log2(e)

typedef __attribute__((ext_vector_type(8))) short bf16x8;
typedef __attribute__((ext_vector_type(4))) float f32x4;

__device__ __forceinline__ short f2bf(float f) {
    union { float f; unsigned u; } x; x.f = f;
    unsigned r = x.u + 0x7FFF + ((x.u >> 16) & 1);
    return (short)(r >> 16);
}
__device__ __forceinline__ float bf2f(short s) {
    union { unsigned u; float f; } x; x.u = ((unsigned)(unsigned short)s) << 16;
    return x.f;
}
__device__ __forceinline__ int qperm(int c) { return ((c & 15) << 2) | (c >> 4); }
__device__ __forceinline__ int sigperm(int c) { return ((c & 3) << 4) | (c >> 2); }

// ====== MERGED: setup (blocks 0-5) ∥ histogram (blocks 6..396), 512 thr ======
__global__ void setup_hist_kernel(const float* __restrict__ I,
                                  const float* __restrict__ m0_wq, const float* __restrict__ m0_bq,
                                  const float* __restrict__ m0_wk, const float* __restrict__ m0_bk,
                                  const float* __restrict__ m0_wv, const float* __restrict__ m0_bv,
                                  const float* __restrict__ m1_wq, const float* __restrict__ m1_bq,
                                  const float* __restrict__ m0_wo, const float* __restrict__ m1_wk,
                                  const float* __restrict__ m1_wv, const float* __restrict__ m1_wo,
                                  float* __restrict__ QI, float* __restrict__ bias160,
                                  short* __restrict__ Wt0, short* __restrict__ WtO,
                                  short* __restrict__ WtK, short* __restrict__ WtV,
                                  short* __restrict__ WtF,
                                  const int* __restrict__ edge, int* __restrict__ cnt) {
    __shared__ float QIs[512];
    __shared__ float Wf[2048];
    __shared__ float bfS[32];
    int tid = threadIdx.x, bid = blockIdx.x;
    if (bid >= 6) {           // histogram part (cnt pre-zeroed by memsetAsync)
        int m = (bid - 6) * 512 + tid;
        if (m < MINC) atomicAdd(&cnt[edge[m]], 1);
        return;
    }
    {
        int i = tid >> 6, c = tid & 63;
        float acc = m0_bq[c];
        for (int k = 0; k < 64; ++k) acc += I[i * 64 + k] * m0_wq[k * 64 + c];
        QIs[tid] = acc;
    }
    __syncthreads();
    if (bid == 0) {
        QI[tid] = QIs[tid];
        if (tid < 32) {
            int i = tid >> 2, h = tid & 3;
            float s = 0.f;
            for (int d = 0; d < 16; ++d)
                s += m0_bk[h * 16 + d] * QIs[i * 64 + h * 16 + d];
            bfS[tid] = s * SCALE_LOG2E;
        }
        __syncthreads();
        if (tid < 160)
            bias160[tid] = (tid < 64) ? m0_bv[tid]
                         : ((tid < 96) ? bfS[tid - 64] : m1_bq[tid - 96]);
    } else if (bid == 1) {
        for (int idx = tid; idx < 2048; idx += 512) {
            int k = idx >> 5, j = idx & 31;
            int i = j >> 2, h = j & 3;
            float s = 0.f;
            for (int d = 0; d < 16; ++d)
                s += m0_wk[k * 64 + h * 16 + d] * QIs[i * 64 + h * 16 + d];
            Wf[idx] = s * SCALE_LOG2E;
        }
        __syncthreads();
        for (int idx = tid; idx < 160 * 72; idx += 512) {
            int c = idx / 72, k = idx % 72;
            short v = 0;
            if (k < 64) {
                float f = (c < 64) ? m0_wv[k * 64 + c]
                        : (c < 96) ? Wf[k * 32 + (c - 64)]
                                   : m1_wq[k * 64 + (c - 96)];
                v = f2bf(f);
            }
            Wt0[idx] = v;
        }
    } else {
        int mat = bid - 2;
        const float* W = (mat == 0) ? m0_wo : (mat == 1) ? m1_wk : (mat == 2) ? m1_wv : m1_wo;
        short* D = (mat == 0) ? WtO : (mat == 1) ? WtK : (mat == 2) ? WtV : WtF;
        bool cperm = (mat == 0);
        for (int idx = tid; idx < 64 * 72; idx += 512) {
            int c = idx / 72, k = idx % 72;
            short v = 0;
            if (k < 64) {
                int kk = qperm(k);
                int cc = cperm ? qperm(c) : c;
                v = f2bf(W[kk * 64 + cc]);
            }
            D[idx] = v;
        }
    }
}

// ====== MERGED: segment-base alloc (blocks 0..78, wave atomic bump) ∥ X GEMM ======
#define NALLOCB ((NEDGE + 255) / 256)   // 79
__global__ void gemmx_alloc_kernel(const float* __restrict__ A,
                                   const short* __restrict__ Wt, const float* __restrict__ bias,
                                   short* __restrict__ V0, _Float16* __restrict__ S0,
                                   short* __restrict__ Q1,
                                   const int* __restrict__ cnt, int2* __restrict__ rowcnt,
                                   int* __restrict__ cursor, int* __restrict__ total) {
    __shared__ short As[64 * 72];
    __shared__ short Ws[160 * 72];
    int tid = threadIdx.x;     // 256
    if (blockIdx.x < NALLOCB) {   // -------- alloc part --------
        int e = blockIdx.x * 256 + tid;
        int lane = tid & 63;
        int c = (e < NEDGE) ? cnt[e] : 0;
        int v = c;
        #pragma unroll
        for (int off = 1; off < 64; off <<= 1) {
            int t = __shfl_up(v, off);
            if (lane >= off) v += t;
        }
        int wavesum = __shfl(v, 63);
        int base = 0;
        if (lane == 63) base = atomicAdd(total, wavesum);
        base = __shfl(base, 63);
        int excl = base + v - c;
        if (e < NEDGE) {
            rowcnt[e] = make_int2(excl, c);
            cursor[e] = excl;
        }
        return;
    }
    // -------- gemm_x part --------
    int row0 = (blockIdx.x - NALLOCB) * 64;
    {
        const uint4* wsrc = (const uint4*)Wt;
        uint4* wdst = (uint4*)Ws;
        for (int k = tid; k < 1440; k += 256) wdst[k] = wsrc[k];
    }
    {
        int r = tid >> 2, c0 = (tid & 3) * 16;
        int gr = row0 + r;
        float f[16];
        if (gr < NNODES) {
            const float4* src = (const float4*)(A + (size_t)gr * 64 + c0);
            #pragma unroll
            for (int j = 0; j < 4; ++j) {
                float4 t4 = src[j];
                f[4*j] = t4.x; f[4*j+1] = t4.y; f[4*j+2] = t4.z; f[4*j+3] = t4.w;
            }
        } else {
            #pragma unroll
            for (int j = 0; j < 16; ++j) f[j] = 0.f;
        }
        short tmp[16];
        #pragma unroll
        for (int j = 0; j < 16; ++j) tmp[j] = f2bf(f[j]);
        uint4* dst = (uint4*)&As[r * 72 + c0];
        dst[0] = *(const uint4*)&tmp[0];
        dst[1] = *(const uint4*)&tmp[8];
    }
    __syncthreads();
    int w = tid >> 6, l = tid & 63;
    int lr16 = l & 15, lk = (l >> 4) * 8;
    f32x4 acc[10] = {};
    #pragma unroll
    for (int ks = 0; ks < 2; ++ks) {
        bf16x8 a = *(const bf16x8*)&As[(w * 16 + lr16) * 72 + ks * 32 + lk];
        #pragma unroll
        for (int t = 0; t < 10; ++t) {
            bf16x8 b = *(const bf16x8*)&Ws[(t * 16 + lr16) * 72 + ks * 32 + lk];
            acc[t] = __builtin_amdgcn_mfma_f32_16x16x32_bf16(a, b, acc[t], 0, 0, 0);
        }
    }
    int rbase = w * 16 + (l >> 4) * 4;
    #pragma unroll
    for (int t = 0; t < 10; ++t) {
        int c = t * 16 + lr16;
        float bb = bias[c];
        #pragma unroll
        for (int r = 0; r < 4; ++r) {
            int gr = row0 + rbase + r;
            if (gr < NNODES) {
                float val = acc[t][r] + bb;
                if (c < 64) V0[(size_t)gr * 64 + c] = f2bf(val);
                else if (c < 96) S0[(size_t)gr * 32 + (c - 64)] = (_Float16)val;
                else Q1[(size_t)gr * 64 + (c - 96)] = f2bf(val);
            }
        }
    }
}

__global__ void scatter_kernel(const int* __restrict__ node, const int* __restrict__ edge,
                               int* __restrict__ cursor, int2* __restrict__ csr_nm) {
    int m = blockIdx.x * 256 + threadIdx.x;
    if (m < MINC) {
        int e = edge[m];
        int pos = atomicAdd(&cursor[e], 1);
        csr_nm[pos] = make_int2(node[m], m);
    }
}

// ============ mab0 attention: ONE WAVE PER EDGE, LDS index staging, paired PV ============
#define CH0 32
__global__ void attn0_kernel(const short* __restrict__ V0, const _Float16* __restrict__ S0,
                             const float* __restrict__ QI,
                             const int2* __restrict__ rowcnt, const int2* __restrict__ csr_nm,
                             short* __restrict__ Opre0) {
    __shared__ float Sw[4][CH0][32];
    __shared__ float Sc[4][32];
    __shared__ float Li[4][32];
    __shared__ int   Ns[4][CH0];
    int w = threadIdx.x >> 6;
    int lane = threadIdx.x & 63;
    int e = blockIdx.x * 4 + w;
    int2 rc = rowcnt[e];
    int start = rc.x, end = rc.x + rc.y;
    int j = lane & 31;                       // i*4+h
    int pslot = lane >> 5;
    int tj = ((j & 3) << 3) | (j >> 2);      // h*8+i
    int col2 = lane & 31;                    // packed col pair: dims 2*col2, 2*col2+1
    int hh = col2 >> 3;                      // head for PV weights
    float runm = -INFINITY, lrun = 0.f;
    float accL[8] = {}, accH[8] = {};
    for (int c0 = start; c0 < end; c0 += CH0) {
        int cnt = min(CH0, end - c0);
        if (lane < CH0) {
            int idx = c0 + min(lane, cnt - 1);
            Ns[w][lane] = csr_nm[idx].x;
        }
        asm volatile("s_waitcnt lgkmcnt(0)" ::: "memory");
        __builtin_amdgcn_sched_barrier(0);
        float cm = -INFINITY;
        for (int p = pslot; p < cnt; p += 2) {
            int n = Ns[w][p];
            float s = (float)S0[(size_t)n * 32 + j];
            Sw[w][p][tj] = s;
            cm = fmaxf(cm, s);
        }
        cm = fmaxf(cm, __shfl_xor(cm, 32));
        float newm = fmaxf(runm, cm);
        float sc = exp2f(runm - newm);
        runm = newm;
        float lsum = 0.f;
        for (int p = pslot; p < cnt; p += 2) {
            float s = Sw[w][p][tj];
            float w_ = exp2f(s - newm);
            Sw[w][p][tj] = w_;
            lsum += w_;
        }
        lsum += __shfl_xor(lsum, 32);
        lrun = lrun * sc + lsum;
        if (pslot == 0) Sc[w][tj] = sc;
        asm volatile("s_waitcnt lgkmcnt(0)" ::: "memory");
        __builtin_amdgcn_sched_barrier(0);
        float4 sA = *(const float4*)&Sc[w][hh * 8];
        float4 sB = *(const float4*)&Sc[w][hh * 8 + 4];
        accL[0] *= sA.x; accH[0] *= sA.x;
        accL[1] *= sA.y; accH[1] *= sA.y;
        accL[2] *= sA.z; accH[2] *= sA.z;
        accL[3] *= sA.w; accH[3] *= sA.w;
        accL[4] *= sB.x; accH[4] *= sB.x;
        accL[5] *= sB.y; accH[5] *= sB.y;
        accL[6] *= sB.z; accH[6] *= sB.z;
        accL[7] *= sB.w; accH[7] *= sB.w;
        int npair = (cnt + 1) >> 1;
        #pragma unroll 4
        for (int k = 0; k < npair; ++k) {
            int rp = 2 * k + pslot;
            bool vld = rp < cnt;
            int rc2 = vld ? rp : (cnt - 1);
            int n = Ns[w][rc2];
            unsigned vp = *(const unsigned*)&V0[(size_t)n * 64 + col2 * 2];
            float vlo = vld ? __int_as_float(vp << 16) : 0.f;
            float vhi = vld ? __int_as_float(vp & 0xffff0000u) : 0.f;
            float4 wA = *(const float4*)&Sw[w][rc2][hh * 8];
            float4 wB = *(const float4*)&Sw[w][rc2][hh * 8 + 4];
            accL[0] += wA.x * vlo; accH[0] += wA.x * vhi;
            accL[1] += wA.y * vlo; accH[1] += wA.y * vhi;
            accL[2] += wA.z * vlo; accH[2] += wA.z * vhi;
            accL[3] += wA.w * vlo; accH[3] += wA.w * vhi;
            accL[4] += wB.x * vlo; accH[4] += wB.x * vhi;
            accL[5] += wB.y * vlo; accH[5] += wB.y * vhi;
            accL[6] += wB.z * vlo; accH[6] += wB.z * vhi;
            accL[7] += wB.w * vlo; accH[7] += wB.w * vhi;
        }
    }
    if (pslot == 0) Li[w][tj] = lrun;
    asm volatile("s_waitcnt lgkmcnt(0)" ::: "memory");
    __builtin_amdgcn_sched_barrier(0);
    #pragma unroll
    for (int i = 0; i < 8; ++i) {
        accL[i] += __shfl_xor(accL[i], 32);
        accH[i] += __shfl_xor(accH[i], 32);
    }
    float4 lA = *(const float4*)&Li[w][hh * 8];
    float4 lB = *(const float4*)&Li[w][hh * 8 + 4];
    float li[8] = {lA.x, lA.y, lA.z, lA.w, lB.x, lB.y, lB.z, lB.w};
    if (pslot == 0) {
        #pragma unroll
        for (int i = 0; i < 8; ++i) {
            float2 qi2 = *(const float2*)&QI[i * 64 + col2 * 2];
            float inv = (li[i] > 0.f) ? 1.f / li[i] : 0.f;
            float ol = qi2.x + accL[i] * inv;
            float oh = qi2.y + accH[i] * inv;
            unsigned res = ((unsigned)(unsigned short)f2bf(oh) << 16)
                         | (unsigned)(unsigned short)f2bf(ol);
            *(unsigned*)&Opre0[(size_t)(e * NIND + i) * 64 + col2 * 2] = res;
        }
    }
}

// === MERGED fused_hkv + attn1 (64 rows = 8 edges per block), weights direct from L1/L2 ===
__global__ void fused_hkv_attn1_kernel(const short* __restrict__ Opre0,
                                       const short* __restrict__ WtO, const float* __restrict__ bo,
                                       const short* __restrict__ WtK, const float* __restrict__ bk,
                                       const short* __restrict__ WtV, const float* __restrict__ bv,
                                       const short* __restrict__ Q1,
                                       const int2* __restrict__ rowcnt,
                                       const int2* __restrict__ csr_nm,
                                       short* __restrict__ Opre1) {
    __shared__ short As[64 * 72];     // A -> H -> K(prescaled)
    __shared__ short Vls[64 * 72];    // V
    int tid = threadIdx.x;   // 256
    int row0 = blockIdx.x * 64;   // 160000 % 64 == 0
    {
        int r = tid >> 2, c0 = (tid & 3) * 16;
        const uint4* src = (const uint4*)(Opre0 + (size_t)(row0 + r) * 64 + c0);
        uint4* dst = (uint4*)&As[r * 72 + c0];
        dst[0] = src[0]; dst[1] = src[1];
    }
    __syncthreads();
    int w = tid >> 6, lane = tid & 63;
    int lr16 = lane & 15, lk = (lane >> 4) * 8;
    int rbase = w * 16 + (lane >> 4) * 4;
    {   // GEMM1: H in-place (wave w only touches rows [w*16, (w+1)*16))
        f32x4 acc[4] = {};
        #pragma unroll
        for (int ks = 0; ks < 2; ++ks) {
            bf16x8 a = *(const bf16x8*)&As[(w * 16 + lr16) * 72 + ks * 32 + lk];
            #pragma unroll
            for (int t = 0; t < 4; ++t) {
                bf16x8 b = *(const bf16x8*)&WtO[(t * 16 + lr16) * 72 + ks * 32 + lk];
                acc[t] = __builtin_amdgcn_mfma_f32_16x16x32_bf16(a, b, acc[t], 0, 0, 0);
            }
        }
        #pragma unroll
        for (int t = 0; t < 4; ++t) {
            int c = t * 16 + lr16;
            float bb = bo[qperm(c)];
            #pragma unroll
            for (int r = 0; r < 4; ++r) {
                float res = bf2f(As[(rbase + r) * 72 + c]);
                float hv = res + fmaxf(acc[t][r] + bb, 0.f);
                As[(rbase + r) * 72 + c] = f2bf(hv);
            }
        }
    }
    {   // GEMM2/3 -> K (prescaled) overwrites As rows; V -> Vls (all wave-private)
        f32x4 ak[4] = {}, av[4] = {};
        #pragma unroll
        for (int ks = 0; ks < 2; ++ks) {
            bf16x8 a = *(const bf16x8*)&As[(w * 16 + lr16) * 72 + ks * 32 + lk];
            #pragma unroll
            for (int t = 0; t < 4; ++t) {
                bf16x8 b1 = *(const bf16x8*)&WtK[(t * 16 + lr16) * 72 + ks * 32 + lk];
                ak[t] = __builtin_amdgcn_mfma_f32_16x16x32_bf16(a, b1, ak[t], 0, 0, 0);
                bf16x8 b2 = *(const bf16x8*)&WtV[(t * 16 + lr16) * 72 + ks * 32 + lk];
                av[t] = __builtin_amdgcn_mfma_f32_16x16x32_bf16(a, b2, av[t], 0, 0, 0);
            }
        }
        #pragma unroll
        for (int t = 0; t < 4; ++t) {
            int c = t * 16 + lr16;
            float bbk = bk[c], bbv = bv[c];
            #pragma unroll
            for (int r = 0; r < 4; ++r) {
                int rr = rbase + r;
                As[rr * 72 + c]  = f2bf((ak[t][r] + bbk) * SCALE_LOG2E);
                Vls[rr * 72 + c] = f2bf(av[t][r] + bbv);
            }
        }
    }
    // ---- attn1 phase: each wave handles its OWN 2 edges; K/V from wave-private LDS ----
    int sl4 = lane & 15;
    int inc = lane >> 4;
    for (int le = 0; le < 2; ++le) {
        int eloc = w * 2 + le;               // 0..7
        int e = blockIdx.x * 8 + eloc;
        int lr0 = eloc * 8;                  // local row base (within wave-own rows)
        float Kf[8][4], Vf[8][4];
        #pragma unroll
        for (int i = 0; i < 8; ++i) {
            uint2 kp = *(const uint2*)&As[(lr0 + i) * 72 + sl4 * 4];
            uint2 vp = *(const uint2*)&Vls[(lr0 + i) * 72 + sl4 * 4];
            Kf[i][0] = __int_as_float(kp.x << 16);
            Kf[i][1] = __int_as_float(kp.x & 0xffff0000u);
            Kf[i][2] = __int_as_float(kp.y << 16);
            Kf[i][3] = __int_as_float(kp.y & 0xffff0000u);
            Vf[i][0] = __int_as_float(vp.x << 16);
            Vf[i][1] = __int_as_float(vp.x & 0xffff0000u);
            Vf[i][2] = __int_as_float(vp.y << 16);
            Vf[i][3] = __int_as_float(vp.y & 0xffff0000u);
        }
        #pragma unroll
        for (int i = 0; i < 8; ++i) {
            #pragma unroll
            for (int d = 0; d < 4; ++d) {
                asm volatile("" : "+v"(Kf[i][d]), "+v"(Vf[i][d]));
            }
        }
        int2 rc = rowcnt[e];
        int start = rc.x, end = rc.x + rc.y;
        #pragma unroll 4
        for (int p0 = start; p0 < end; p0 += 4) {
            int p = p0 + inc;
            bool valid = (p < end);
            int pc = valid ? p : (end - 1);
            int2 nm = csr_nm[pc];
            uint2 qp = *(const uint2*)&Q1[(size_t)nm.x * 64 + sl4 * 4];
            float qa0 = __int_as_float(qp.x << 16);
            float qa1 = __int_as_float(qp.x & 0xffff0000u);
            float qa2 = __int_as_float(qp.y << 16);
            float qa3 = __int_as_float(qp.y & 0xffff0000u);
            float a[8];
            #pragma unroll
            for (int i = 0; i < 8; ++i) {
                float t = qa0 * Kf[i][0] + qa1 * Kf[i][1] + qa2 * Kf[i][2] + qa3 * Kf[i][3];
                int tv = __builtin_amdgcn_update_dpp(0, __float_as_int(t), 0xB1, 0xf, 0xf, true);
                t += __int_as_float(tv);
                tv = __builtin_amdgcn_update_dpp(0, __float_as_int(t), 0x4E, 0xf, 0xf, true);
                t += __int_as_float(tv);
                a[i] = t;                                 // log2-domain score
            }
            float mx = fmaxf(fmaxf(fmaxf(a[0], a[1]), fmaxf(a[2], a[3])),
                             fmaxf(fmaxf(a[4], a[5]), fmaxf(a[6], a[7])));
            float l = 0.f, ac0 = 0.f, ac1 = 0.f, ac2 = 0.f, ac3 = 0.f;
            #pragma unroll
            for (int i = 0; i < 8; ++i) {
                float w_ = exp2f(a[i] - mx);
                l += w_;
                ac0 += w_ * Vf[i][0];
                ac1 += w_ * Vf[i][1];
                ac2 += w_ * Vf[i][2];
                ac3 += w_ * Vf[i][3];
            }
            float rl = 1.f / l;
            float o0 = qa0 + ac0 * rl;
            float o1 = qa1 + ac1 * rl;
            float o2 = qa2 + ac2 * rl;
            float o3 = qa3 + ac3 * rl;
            uint2 res;
            res.x = ((unsigned)(unsigned short)f2bf(o1) << 16) | (unsigned)(unsigned short)f2bf(o0);
            res.y = ((unsigned)(unsigned short)f2bf(o3) << 16) | (unsigned)(unsigned short)f2bf(o2);
            if (valid) *(uint2*)&Opre1[(size_t)nm.y * 64 + sl4 * 4] = res;
        }
    }
}

// ======= final GEMM (128 rows/block): out = res + relu(A@w+b), perm baked, NT stores =======
__global__ void gemm_out_kernel(const short* __restrict__ Av,
                                const short* __restrict__ Wt, const float* __restrict__ bias,
                                float* __restrict__ out) {
    __shared__ short As[128 * 72];
    __shared__ short Ws[64 * 72];
    int tid = threadIdx.x;     // 256
    int row0 = blockIdx.x * 128;
    {
        const uint4* wsrc = (const uint4*)Wt;
        uint4* wdst = (uint4*)Ws;
        for (int k = tid; k < 576; k += 256) wdst[k] = wsrc[k];
    }
    #pragma unroll
    for (int it = 0; it < 2; ++it) {
        int slot = tid + it * 256;
        int r = slot >> 2, c0 = (slot & 3) * 16;
        int gr = row0 + r;
        uint4 a0 = {}, a1 = {};
        if (gr < MINC) {
            const uint4* src = (const uint4*)(Av + (size_t)gr * 64 + c0);
            a0 = src[0]; a1 = src[1];
        }
        uint4* dst = (uint4*)&As[r * 72 + c0];
        dst[0] = a0; dst[1] = a1;
    }
    __syncthreads();
    int w = tid >> 6, l = tid & 63;
    int lr16 = l & 15, lk = (l >> 4) * 8;
    f32x4 acc[2][4] = {};
    #pragma unroll
    for (int ks = 0; ks < 2; ++ks) {
        bf16x8 a0 = *(const bf16x8*)&As[(w * 16 + lr16) * 72 + ks * 32 + lk];
        bf16x8 a1 = *(const bf16x8*)&As[(64 + w * 16 + lr16) * 72 + ks * 32 + lk];
        #pragma unroll
        for (int t = 0; t < 4; ++t) {
            bf16x8 b = *(const bf16x8*)&Ws[(t * 16 + lr16) * 72 + ks * 32 + lk];
            acc[0][t] = __builtin_amdgcn_mfma_f32_16x16x32_bf16(a0, b, acc[0][t], 0, 0, 0);
            acc[1][t] = __builtin_amdgcn_mfma_f32_16x16x32_bf16(a1, b, acc[1][t], 0, 0, 0);
        }
    }
    int rbase = w * 16 + (l >> 4) * 4;
    #pragma unroll
    for (int rt = 0; rt < 2; ++rt) {
        #pragma unroll
        for (int t = 0; t < 4; ++t) {
            int c = t * 16 + lr16;
            float bb = bias[c];
            int sc = sigperm(c);
            #pragma unroll
            for (int r = 0; r < 4; ++r) {
                int gr = row0 + rt * 64 + rbase + r;
                if (gr < MINC) {
                    float val = acc[rt][t][r] + bb;
                    float res = bf2f(As[(rt * 64 + rbase + r) * 72 + sc]);
                    __builtin_nontemporal_store(res + fmaxf(val, 0.f),
                                                &out[(size_t)gr * 64 + c]);
                }
            }
        }
    }
}

// ===================== host launch =====================
extern "C" void kernel_launch(void* const* d_in, const int* in_sizes, int n_in,
                              void* d_out, int out_size, void* d_ws, size_t ws_size,
                              hipStream_t stream) {
    const float* X    = (const float*)d_in[0];
    const int*   hei  = (const int*)d_in[1];
    const float* I    = (const float*)d_in[2];
    const float* m0_wq = (const float*)d_in[3];
    const float* m0_bq = (const float*)d_in[4];
    const float* m0_wk = (const float*)d_in[5];
    const float* m0_bk = (const float*)d_in[6];
    const float* m0_wv = (const float*)d_in[7];
    const float* m0_bv = (const float*)d_in[8];
    const float* m0_wo = (const float*)d_in[9];
    const float* m0_bo = (const float*)d_in[10];
    const float* m1_wq = (const float*)d_in[11];
    const float* m1_bq = (const float*)d_in[12];
    const float* m1_wk = (const float*)d_in[13];
    const float* m1_bk = (const float*)d_in[14];
    const float* m1_wv = (const float*)d_in[15];
    const float* m1_bv = (const float*)d_in[16];
    const float* m1_wo = (const float*)d_in[17];
    const float* m1_bo = (const float*)d_in[18];

    const int* node = hei;           // [M]
    const int* edge = hei + MINC;    // [M]
    float* out = (float*)d_out;

    // -------- workspace layout (byte offsets) --------
    char* B = (char*)d_ws;
    short* Opre0 = (short*)B;                    // 20.48 MB
    short* V0    = (short*)(B + 20480000);       // 6.4 MB
    _Float16* S0 = (_Float16*)(B + 26880000);    // 3.2 MB
    short* Opre1 = (short*)(B + 33280000);       // 25.6 MB
    short* Q1    = (short*)(B + 74240000);       // 6.4 MB
    float* QI    = (float*)(B + 80640000);       // 512 f
    float* bias160 = QI + 512;                   // 160 f
    short* PK    = (short*)(bias160 + 160);
    short* Wt0   = PK;                           // 160*72
    short* WtO   = PK + 11520;
    short* WtK   = WtO + 4608;
    short* WtV   = WtK + 4608;
    short* WtF   = WtV + 4608;
    int*   ib       = (int*)(((size_t)(WtF + 4608) + 7) & ~(size_t)7);
    int2*  rowcnt   = (int2*)ib;                 // NE int2
    int*   cnt      = (int*)(rowcnt + NEDGE);    // NE  (memset region starts here)
    int*   total    = cnt + NEDGE;               // 1   (zeroed with cnt)
    int*   cursor   = total + 1;                 // NE
    int2*  csr_nm   = (int2*)(((size_t)(cursor + NEDGE) + 7) & ~(size_t)7);  // M int2

    // ---------------- setup ∥ hist, then alloc ∥ gemm_x, then scatter ----------------
    hipMemsetAsync(cnt, 0, (NEDGE + 1) * sizeof(int), stream);
    setup_hist_kernel<<<6 + (MINC + 511) / 512, 512, 0, stream>>>(
        I, m0_wq, m0_bq, m0_wk, m0_bk, m0_wv, m0_bv,
        m1_wq, m1_bq, m0_wo, m1_wk, m1_wv, m1_wo,
        QI, bias160, Wt0, WtO, WtK, WtV, WtF, edge, cnt);
    gemmx_alloc_kernel<<<NALLOCB + (NNODES + 63) / 64, 256, 0, stream>>>(
        X, Wt0, bias160, V0, S0, Q1, cnt, rowcnt, cursor, total);
    scatter_kernel<<<(MINC + 255) / 256, 256, 0, stream>>>(node, edge, cursor, csr_nm);

    // ---------------- Phase A: mab0 ----------------
    attn0_kernel<<<NEDGE / 4, 256, 0, stream>>>(V0, S0, QI, rowcnt, csr_nm, Opre0);

    // ---------------- Phase B: mab1 (fused H/K/V GEMMs + attention) ----------------
    fused_hkv_attn1_kernel<<<NEDGE / 8, 256, 0, stream>>>(
        Opre0, WtO, m0_bo, WtK, m1_bk, WtV, m1_bv, Q1, rowcnt, csr_nm, Opre1);
    gemm_out_kernel<<<(MINC + 127) / 128, 256, 0, stream>>>(Opre1, WtF, m1_bo, out);
}